// Round 12
// baseline (60.276 us; speedup 1.0000x reference)
//
#include <hip/hip_runtime.h>
#include <math.h>

#define NBATCH 32
#define AP     75600   // anchors per sample = 25200*27/9
#define NF     9       // 4 box + 1 obj + 4 cls
#define KTOP   300
#define NT     50
#define NC     4
#define NBLKA  296     // one-anchor-per-thread blocks per sample (R1-proven shape)
#define LCAP   64      // per-block candidate slots (expect ~6/block)
#define CCAPL  3072    // kB LDS candidate capacity (expect ~1723)
#define MCAP   384     // member (top-300) capacity
#define EQCAP  1024    // ==T tie list capacity
#define PREFK  0xC0000000u   // fkey(2.0f): conservative prefilter threshold

__device__ __forceinline__ float sp_f(float x){           // jax.nn.softplus
    return fmaxf(x, 0.0f) + log1pf(expf(-fabsf(x)));
}
__device__ __forceinline__ float sig_f(float x){
    return 1.0f / (1.0f + expf(-x));
}
// monotone float->uint key (descending float order == descending uint order)
__device__ __forceinline__ unsigned fkey(float x){
    unsigned u = __float_as_uint(x);
    return (u & 0x80000000u) ? ~u : (u | 0x80000000u);
}
__device__ __forceinline__ float kinv(unsigned k){
    unsigned u = (k & 0x80000000u) ? (k & 0x7FFFFFFFu) : ~k;
    return __uint_as_float(u);
}

// ============================ FAST PATH (3 kernels) =========================

// kA: R1-proven shape — 9472 tiny blocks, ONE anchor per thread. R10 (float4)
// and R11 (8-deep MLP) both null/regressed at 1184 big blocks; R1 measured
// this exact access pattern + block shape at ~15-19 us. Body adds softplus
// (f32) + prefilter slot write. Plain stores, no zeroing, no global atomics.
__global__ __launch_bounds__(256) void kA_scan(
    const float* __restrict__ pred, double* __restrict__ partials,
    unsigned* __restrict__ candKey, int* __restrict__ candIdx,
    int* __restrict__ candCnt)
{
    const int s   = blockIdx.y;
    const int blk = blockIdx.x;
    const int tid = threadIdx.x;
    __shared__ unsigned bKey[LCAP];
    __shared__ int      bIdx[LCAP];
    __shared__ int      lcnt;
    __shared__ double   wsum[4];
    if (tid == 0) lcnt = 0;
    __syncthreads();

    const float* p_s = pred + (size_t)s * (AP*NF);
    const int a = blk*256 + tid;
    const bool ok = (a < AP);
    float o = ok ? p_s[(size_t)a*NF + 4] : -1.0f;
    float facc = ok ? sp_f(o) : 0.0f;
    if (ok){
        unsigned ky = fkey(o);
        if (ky >= PREFK){
            int p = atomicAdd(&lcnt, 1);          // LDS atomic, ~6 per block
            if (p < LCAP){ bKey[p] = ky; bIdx[p] = a; }
        }
    }
    double acc = (double)facc;
    for (int off = 32; off > 0; off >>= 1) acc += __shfl_down(acc, off);
    if ((tid & 63) == 0) wsum[tid >> 6] = acc;
    __syncthreads();
    if (tid == 0){
        partials[s*NBLKA + blk] = wsum[0] + wsum[1] + wsum[2] + wsum[3];
        candCnt[s*NBLKA + blk] = lcnt;            // raw (overflow detector)
    }
    const int n = min(lcnt, LCAP);
    unsigned* gk = candKey + ((size_t)s*NBLKA + blk) * LCAP;
    int*      gi = candIdx + ((size_t)s*NBLKA + blk) * LCAP;
    for (int i = tid; i < n; i += 256){ gk[i] = bKey[i]; gi[i] = bIdx[i]; }
}

// wave-parallel descending find-bin over ngroups*64 bins:
// find b with above(b) < need <= above(b)+hist[b]; above = sum of bins > b.
__device__ __forceinline__ void find_bin_wp(
    const unsigned* hist, int ngroups, unsigned need,
    unsigned* sGS, unsigned* sBin, unsigned* sAbove, int tid)
{
    const int wv = tid >> 6, ln = tid & 63;
    for (int g = wv; g < ngroups; g += 16){
        unsigned v = hist[g*64 + ln];
        #pragma unroll
        for (int off = 32; off > 0; off >>= 1){
            unsigned t = __shfl_down(v, off);
            if (ln + off < 64) v += t;
        }
        if (ln == 0) sGS[g] = v;
    }
    __syncthreads();
    if (wv == 0){
        unsigned gsv = (ln < ngroups) ? sGS[ln] : 0u;
        unsigned inc = gsv;                       // suffix-inclusive over groups
        #pragma unroll
        for (int off = 1; off < 64; off <<= 1){
            unsigned t = __shfl_down(inc, off);
            if (ln + off < 64) inc += t;
        }
        unsigned excl = inc - gsv;                // groups strictly above
        bool hit = (ln < ngroups) && (excl < need) && (need <= inc);
        unsigned long long mb = __ballot(hit);
        int gstar = __ffsll(mb) - 1;              // unique crossing group
        unsigned exG = __shfl(excl, gstar);
        unsigned y = hist[gstar*64 + ln];
        unsigned yinc = y;                        // suffix-inclusive within group
        #pragma unroll
        for (int off = 1; off < 64; off <<= 1){
            unsigned t = __shfl_down(yinc, off);
            if (ln + off < 64) yinc += t;
        }
        unsigned above = exG + (yinc - y);
        bool hit2 = (above < need) && (need <= above + y);
        mb = __ballot(hit2);
        int bl = __ffsll(mb) - 1;
        unsigned ab = __shfl(above, bl);
        if (ln == 0){ *sBin = (unsigned)(gstar*64 + bl); *sAbove = ab; }
    }
    __syncthreads();
}

// kB: per sample — chunked wave-scan of 296 block counts, gather ~1723
// candidates into LDS, 3-level radix select of the exact top-300, IoU argmax,
// losses. Exact fallback: stream pred directly if prefilter coverage fails.
__global__ __launch_bounds__(1024) void kB_finish(
    const float* __restrict__ pred,
    const float* __restrict__ tboxG,
    const int*   __restrict__ tclsG,
    const unsigned* __restrict__ candKeyG, const int* __restrict__ candIdxG,
    const int* __restrict__ candCnt,
    const double* __restrict__ partials,
    float* __restrict__ lossPart)
{
    const int s   = blockIdx.x;
    const int tid = threadIdx.x;
    const int wv  = tid >> 6;
    const int ln  = tid & 63;
    const float* p_s = pred + (size_t)s * (AP*NF);

    __shared__ unsigned cKey[CCAPL];
    __shared__ int      cIdx[CCAPL];
    __shared__ unsigned hist[2048];
    __shared__ unsigned sGS[32];
    __shared__ unsigned sB1, sA1, sB2, sA2, sB3, sA3;
    __shared__ int      bOff[NBLKA + 1];
    __shared__ int      sOk;
    __shared__ int      eqList[EQCAP];
    __shared__ int      eqCnt, mCnt;
    __shared__ unsigned mKey[MCAP];
    __shared__ int      mIdx[MCAP];
    __shared__ float    mB[5][MCAP];     // x1,y1,x2,y2,area
    __shared__ float    tXY[NT][5];
    __shared__ float    tWH[NT][4];
    __shared__ int      tCl[NT];
    __shared__ int      chosenA[NT];
    __shared__ float    corrJ[NT], clsJ[NT], boxJ[NT];
    __shared__ int      lastJ[NT];
    __shared__ double   s_spsum;

    // P0: wave-0 chunked scan of 296 block counts (carry across 64-lane
    // chunks); wave-15 chunked reduce of softplus partials
    if (tid == 0){ eqCnt = 0; mCnt = 0; }
    if (wv == 0){
        int carry = 0; int anyof = 0;
        for (int base = 0; base < NBLKA; base += 64){
            int b   = base + ln;
            int raw = (b < NBLKA) ? candCnt[s*NBLKA + b] : 0;
            anyof  |= (raw > LCAP) ? 1 : 0;
            int inc = min(raw, LCAP);
            #pragma unroll
            for (int off = 1; off < 64; off <<= 1){
                int t = __shfl_up(inc, off);
                if (ln >= off) inc += t;
            }
            if (b < NBLKA) bOff[b + 1] = carry + inc;
            carry += __shfl(inc, 63);             // uniform broadcast
        }
        unsigned long long m = __ballot(anyof != 0);
        if (ln == 0){
            bOff[0] = 0;
            sOk = (m == 0ull && carry >= KTOP && carry <= CCAPL) ? 1 : 0;
        }
    }
    if (wv == 15){
        double a = 0.0;
        for (int base = 0; base < NBLKA; base += 64){
            int b = base + ln;
            double v = (b < NBLKA) ? partials[s*NBLKA + b] : 0.0;
            for (int off = 32; off > 0; off >>= 1) v += __shfl_down(v, off);
            if (ln == 0) a += v;
        }
        if (ln == 0) s_spsum = a;
    }
    __syncthreads();
    const bool fast = (sOk != 0);
    const int  n    = fast ? bOff[NBLKA] : 0;

    // P0b: gather candidates into LDS (fast path; ~6 per segment)
    if (fast){
        for (int b = wv; b < NBLKA; b += 16){
            const int c = min(candCnt[s*NBLKA + b], LCAP);
            const int o = bOff[b];
            const unsigned* gk = candKeyG + ((size_t)s*NBLKA + b) * LCAP;
            const int*      gi = candIdxG + ((size_t)s*NBLKA + b) * LCAP;
            for (int i = ln; i < c; i += 64){ cKey[o+i] = gk[i]; cIdx[o+i] = gi[i]; }
        }
    }
    // P1: level-1 histogram (top 11 bits)
    for (int i = tid; i < 2048; i += 1024) hist[i] = 0;
    __syncthreads();
    if (fast){
        for (int i = tid; i < n; i += 1024) atomicAdd(&hist[cKey[i] >> 21], 1u);
    } else {
        for (int i = tid; i < AP; i += 1024)
            atomicAdd(&hist[fkey(p_s[(size_t)i*NF + 4]) >> 21], 1u);
    }
    __syncthreads();
    find_bin_wp(hist, 32, KTOP, sGS, &sB1, &sA1, tid);
    const unsigned b1 = sB1, ab1 = sA1;
    const unsigned need2 = KTOP - ab1;

    // P2: level-2 histogram (bits 20..10) within bin b1
    for (int i = tid; i < 2048; i += 1024) hist[i] = 0;
    __syncthreads();
    if (fast){
        for (int i = tid; i < n; i += 1024){
            unsigned ky = cKey[i];
            if ((ky >> 21) == b1) atomicAdd(&hist[(ky >> 10) & 0x7FFu], 1u);
        }
    } else {
        for (int i = tid; i < AP; i += 1024){
            unsigned ky = fkey(p_s[(size_t)i*NF + 4]);
            if ((ky >> 21) == b1) atomicAdd(&hist[(ky >> 10) & 0x7FFu], 1u);
        }
    }
    __syncthreads();
    find_bin_wp(hist, 32, need2, sGS, &sB2, &sA2, tid);
    const unsigned b2 = sB2, ab2 = sA2;
    const unsigned need3 = need2 - ab2;
    const unsigned pref  = (b1 << 11) | b2;

    // P3: level-3 histogram (bits 9..0) within prefix
    if (tid < 1024) hist[tid] = 0;
    __syncthreads();
    if (fast){
        for (int i = tid; i < n; i += 1024){
            unsigned ky = cKey[i];
            if ((ky >> 10) == pref) atomicAdd(&hist[ky & 0x3FFu], 1u);
        }
    } else {
        for (int i = tid; i < AP; i += 1024){
            unsigned ky = fkey(p_s[(size_t)i*NF + 4]);
            if ((ky >> 10) == pref) atomicAdd(&hist[ky & 0x3FFu], 1u);
        }
    }
    __syncthreads();
    find_bin_wp(hist, 16, need3, sGS, &sB3, &sA3, tid);
    const unsigned b3 = sB3, ab3 = sA3;
    const unsigned needEq = need3 - ab3;
    const unsigned T = (b1 << 21) | (b2 << 10) | b3;

    // P4: collect ==T ties
    if (fast){
        for (int i = tid; i < n; i += 1024){
            if (cKey[i] == T){
                int p = atomicAdd(&eqCnt, 1);
                if (p < EQCAP) eqList[p] = cIdx[i];
            }
        }
    } else {
        for (int i = tid; i < AP; i += 1024){
            if (fkey(p_s[(size_t)i*NF + 4]) == T){
                int p = atomicAdd(&eqCnt, 1);
                if (p < EQCAP) eqList[p] = i;
            }
        }
    }
    __syncthreads();
    const int ne = min(eqCnt, EQCAP);

    // P5: membership (exact top-300 set) + ballot compaction
    const int dom = fast ? n : AP;
    for (int base = wv*64; base < dom; base += 1024){
        int i = base + ln;
        bool mflag = false; unsigned ky = 0; int ix = 0;
        if (i < dom){
            if (fast){ ky = cKey[i]; ix = cIdx[i]; }
            else     { ky = fkey(p_s[(size_t)i*NF + 4]); ix = i; }
            if (ky > T) mflag = true;
            else if (ky == T){
                int r = 0;
                for (int j = 0; j < ne; ++j) r += (eqList[j] < ix) ? 1 : 0;
                mflag = ((unsigned)r < needEq);   // lowest-index ties, lax.top_k order
            }
        }
        unsigned long long msk = __ballot(mflag);
        int bpos = 0;
        if (ln == 0 && msk) bpos = atomicAdd(&mCnt, (int)__popcll(msk));
        bpos = __shfl(bpos, 0);
        if (mflag){
            int pos = bpos + (int)__popcll(msk & ((1ull << ln) - 1ull));
            if (pos < MCAP){ mKey[pos] = ky; mIdx[pos] = ix; }
        }
    }
    __syncthreads();
    const int kM = min(mCnt, MCAP);   // == 300 by construction

    // P6: boxes for members (pred rows are L2/L3-resident after kA) + targets
    for (int m = tid; m < kM; m += 1024){
        const float* row = p_s + (size_t)mIdx[m] * NF;
        float bx = sig_f(row[0]), by = sig_f(row[1]);
        float bw = sig_f(row[2]), bh = sig_f(row[3]);
        float hw = bw * 0.5f, hh = bh * 0.5f;
        float x1 = bx - hw, y1 = by - hh, x2 = bx + hw, y2 = by + hh;
        mB[0][m] = x1; mB[1][m] = y1; mB[2][m] = x2; mB[3][m] = y2;
        mB[4][m] = (x2 - x1) * (y2 - y1);
    }
    if (tid >= 512 && tid < 512 + NT){
        int t = tid - 512;
        const float* tb = tboxG + ((size_t)s * NT + t) * 4;
        float cx = fminf(fmaxf(tb[0], 0.f), 1.f);
        float cy = fminf(fmaxf(tb[1], 0.f), 1.f);
        float w  = fminf(fmaxf(tb[2], 0.f), 1.f);
        float h  = fminf(fmaxf(tb[3], 0.f), 1.f);
        tWH[t][0] = cx; tWH[t][1] = cy; tWH[t][2] = w; tWH[t][3] = h;
        float hw = w * 0.5f, hh = h * 0.5f;
        float x1 = cx - hw, y1 = cy - hh, x2 = cx + hw, y2 = cy + hh;
        tXY[t][0] = x1; tXY[t][1] = y1; tXY[t][2] = x2; tXY[t][3] = y2;
        tXY[t][4] = (x2 - x1) * (y2 - y1);
        int c = tclsG[(size_t)s * NT + t];
        tCl[t] = min(max(c, 0), NC - 1);
    }
    __syncthreads();

    // P7: per-target argmax over the SET by (iou desc, key desc, idx asc)
    for (int t = wv; t < NT; t += 16){
        float tx1 = tXY[t][0], ty1 = tXY[t][1], tx2 = tXY[t][2], ty2 = tXY[t][3];
        float ta  = tXY[t][4];
        float    bIou = -1.0f; unsigned bKy = 0; int bIx = 0x7FFFFFFF;
        for (int m = ln; m < kM; m += 64){
            float iw = fminf(mB[2][m], tx2) - fmaxf(mB[0][m], tx1);
            iw = fmaxf(iw, 0.0f);
            float ih = fminf(mB[3][m], ty2) - fmaxf(mB[1][m], ty1);
            ih = fmaxf(ih, 0.0f);
            float inter = iw * ih;
            float uni = mB[4][m] + ta - inter;
            float iou = (uni > 0.0f) ? (inter / uni) : 0.0f;
            unsigned ky = mKey[m]; int ix = mIdx[m];
            if (iou > bIou || (iou == bIou && (ky > bKy || (ky == bKy && ix < bIx)))){
                bIou = iou; bKy = ky; bIx = ix;
            }
        }
        #pragma unroll
        for (int off = 32; off > 0; off >>= 1){
            float    oI = __shfl_down(bIou, off);
            unsigned oK = __shfl_down(bKy,  off);
            int      oX = __shfl_down(bIx,  off);
            bool take = (ln + off < 64) &&
                        (oI > bIou || (oI == bIou && (oK > bKy || (oK == bKy && oX < bIx))));
            if (take){ bIou = oI; bKy = oK; bIx = oX; }
        }
        if (ln == 0) chosenA[t] = bIx;
    }
    __syncthreads();

    // P8: per-target contributions; duplicates: last j wins rows, cls classes union
    if (tid < NT){
        int a = chosenA[tid];
        bool last = true;
        for (int j2 = tid + 1; j2 < NT; ++j2) if (chosenA[j2] == a) last = false;
        float corr = 0.f, clsv = 0.f, boxv = 0.f;
        if (last){
            const float* row = p_s + (size_t)a * NF;
            float o = row[4];
            float spo = sp_f(o);
            corr = 2.0f * (spo - o) - 0.5f * spo;   // replace 0.5*sp with 2*(sp-x)
            unsigned mask = 0;
            for (int j2 = 0; j2 < NT; ++j2)
                if (chosenA[j2] == a) mask |= (1u << tCl[j2]);
            const float smooth_neg = (float)(0.05 / 3.0);
            for (int c = 0; c < NC; ++c){
                float x = row[5 + c];
                float t = ((mask >> c) & 1u) ? 0.95f : smooth_neg;
                clsv += sp_f(x) - x * t;
            }
            for (int c = 0; c < 4; ++c){
                float p = sig_f(row[c]);
                float d = fabsf(p - tWH[tid][c]);
                boxv += (d < 0.1f) ? (0.5f * d * d / 0.1f) : (d - 0.05f);
            }
        }
        lastJ[tid] = last ? 1 : 0;
        corrJ[tid] = corr; clsJ[tid] = clsv; boxJ[tid] = boxv;
    }
    __syncthreads();

    if (tid == 0){
        double corrS = 0, clsS = 0, boxS = 0; int np = 0;
        for (int j = 0; j < NT; ++j){
            if (lastJ[j]){ np++; corrS += corrJ[j]; clsS += clsJ[j]; boxS += boxJ[j]; }
        }
        float obj_l = (float)((0.5 * s_spsum + corrS) / (double)AP);
        float cls_l = (np > 0) ? (float)(clsS / ((double)np * NC)) : 0.f;
        float box_l = (np > 0) ? (float)(boxS / ((double)np * 4) * 2.0) : 0.f;
        lossPart[s*4 + 0] = box_l;
        lossPart[s*4 + 1] = cls_l;
        lossPart[s*4 + 2] = obj_l;
    }
}

// k5: deterministic final reduce (fixed order; stream-ordered after kB)
__global__ void k5_reduce(const float* __restrict__ lossPart, float* __restrict__ out){
    if (threadIdx.x == 0){
        double b = 0, c = 0, o = 0;
        for (int s2 = 0; s2 < NBATCH; ++s2){
            b += (double)lossPart[s2*4 + 0];
            c += (double)lossPart[s2*4 + 1];
            o += (double)lossPart[s2*4 + 2];
        }
        out[1] = (float)b; out[2] = (float)c; out[3] = (float)o;
        out[0] = (float)(b + c + o);
    }
}

// ============================ FALLBACK (round-1) ============================

__device__ __forceinline__ unsigned load_key(const unsigned* k_s, const float* p_s, int i){
    return k_s ? k_s[i] : fkey(p_s[i*NF + 4]);
}

__global__ void build_keys_kernel(const float* __restrict__ pred, unsigned* __restrict__ keys){
    int s = blockIdx.y;
    int a = blockIdx.x * 256 + threadIdx.x;
    if (a < AP){
        float o = pred[(size_t)s * (AP*NF) + (size_t)a * NF + 4];
        keys[s * AP + a] = fkey(o);
    }
}

__device__ void find_bin(unsigned* hist, unsigned* ssup, int* sbin, unsigned* sabove,
                         unsigned need, int tid){
    if (tid < 32){
        unsigned a2 = 0;
        for (int i = 0; i < 64; ++i) a2 += hist[tid*64 + i];
        ssup[tid] = a2;
    }
    __syncthreads();
    if (tid == 0){
        unsigned a2 = 0; int g = 31;
        for (; g > 0; --g){ if (a2 + ssup[g] >= need) break; a2 += ssup[g]; }
        int b = g*64 + 63;
        for (;;){ unsigned h = hist[b]; if (a2 + h >= need || b == g*64) break; a2 += h; --b; }
        *sbin = b; *sabove = a2;
    }
    __syncthreads();
}

__global__ __launch_bounds__(1024) void loss_kernel_full(
    const float* __restrict__ pred,
    const unsigned* __restrict__ keysG,
    const float* __restrict__ tboxG,
    const int*   __restrict__ tclsG,
    float* __restrict__ out)
{
    const int s   = blockIdx.x;
    const int tid = threadIdx.x;
    const float*    p_s = pred + (size_t)s * (AP*NF);
    const unsigned* k_s = keysG ? (keysG + s * AP) : nullptr;

    __shared__ unsigned hist[2048];
    __shared__ unsigned ssup[32];
    __shared__ int sbin; __shared__ unsigned sabove;
    __shared__ double wsum[16];
    __shared__ double s_spsum;
    __shared__ unsigned tkKey[KTOP]; __shared__ int tkIdx[KTOP];
    __shared__ int eqIdx[2048];
    __shared__ int nGt, nEq;
    __shared__ int sIdx[KTOP];
    __shared__ float cand[KTOP][5];
    __shared__ float tXY[NT][5];
    __shared__ float tWH[NT][4];
    __shared__ int   tCl[NT];
    __shared__ int   chosenA[NT];
    __shared__ float corrJ[NT], clsJ[NT], boxJ[NT];
    __shared__ int   lastJ[NT];

    for (int i = tid; i < 2048; i += 1024) hist[i] = 0;
    if (tid == 0){ nGt = 0; nEq = 0; }
    __syncthreads();
    double acc = 0.0;
    for (int i = tid; i < AP; i += 1024){
        unsigned ky = load_key(k_s, p_s, i);
        atomicAdd(&hist[ky >> 21], 1u);
        acc += (double)sp_f(kinv(ky));
    }
    for (int off = 32; off > 0; off >>= 1) acc += __shfl_down(acc, off);
    if ((tid & 63) == 0) wsum[tid >> 6] = acc;
    __syncthreads();
    if (tid == 0){
        double t = 0.0;
        for (int w = 0; w < 16; ++w) t += wsum[w];
        s_spsum = t;
    }
    __syncthreads();

    find_bin(hist, ssup, &sbin, &sabove, KTOP, tid);
    const int b1 = sbin; const unsigned above1 = sabove;
    const unsigned need2 = KTOP - above1;
    __syncthreads();

    for (int i = tid; i < 2048; i += 1024) hist[i] = 0;
    __syncthreads();
    for (int i = tid; i < AP; i += 1024){
        unsigned ky = load_key(k_s, p_s, i);
        if ((int)(ky >> 21) == b1) atomicAdd(&hist[(ky >> 10) & 0x7FFu], 1u);
    }
    __syncthreads();
    find_bin(hist, ssup, &sbin, &sabove, need2, tid);
    const int b2 = sbin; const unsigned above2 = sabove;
    const unsigned need3 = need2 - above2;
    const unsigned pref  = ((unsigned)b1 << 11) | (unsigned)b2;
    __syncthreads();

    for (int i = tid; i < 2048; i += 1024) hist[i] = 0;
    __syncthreads();
    for (int i = tid; i < AP; i += 1024){
        unsigned ky = load_key(k_s, p_s, i);
        if ((ky >> 10) == pref) atomicAdd(&hist[ky & 0x3FFu], 1u);
    }
    __syncthreads();
    find_bin(hist, ssup, &sbin, &sabove, need3, tid);
    const int b3 = sbin; const unsigned above3 = sabove;
    const unsigned needEq = need3 - above3;
    const unsigned T      = ((unsigned)b1 << 21) | ((unsigned)b2 << 10) | (unsigned)b3;
    const unsigned cntGt  = above1 + above2 + above3;
    __syncthreads();

    for (int i = tid; i < AP; i += 1024){
        unsigned ky = load_key(k_s, p_s, i);
        if (ky > T){
            int p = atomicAdd(&nGt, 1);
            if (p < KTOP){ tkKey[p] = ky; tkIdx[p] = i; }
        } else if (ky == T){
            int p = atomicAdd(&nEq, 1);
            if (p < 2048) eqIdx[p] = i;
        }
    }
    __syncthreads();
    {
        int ne = min(nEq, 2048);
        for (int t = tid; t < ne; t += 1024){
            int mine = eqIdx[t]; int r = 0;
            for (int j = 0; j < ne; ++j) r += (eqIdx[j] < mine) ? 1 : 0;
            if ((unsigned)r < needEq){
                int p = (int)cntGt + r;
                if (p < KTOP){ tkKey[p] = T; tkIdx[p] = mine; }
            }
        }
    }
    __syncthreads();

    if (tid < KTOP){
        unsigned myk = tkKey[tid]; int myi = tkIdx[tid];
        int r = 0;
        for (int j = 0; j < KTOP; ++j){
            unsigned kj = tkKey[j]; int ij = tkIdx[j];
            r += (kj > myk || (kj == myk && ij < myi)) ? 1 : 0;
        }
        sIdx[r] = myi;
    }
    __syncthreads();

    if (tid < KTOP){
        int a = sIdx[tid];
        const float* row = p_s + a * NF;
        float bx = sig_f(row[0]), by = sig_f(row[1]);
        float bw = sig_f(row[2]), bh = sig_f(row[3]);
        float hw = bw * 0.5f, hh = bh * 0.5f;
        float x1 = bx - hw, y1 = by - hh, x2 = bx + hw, y2 = by + hh;
        cand[tid][0] = x1; cand[tid][1] = y1; cand[tid][2] = x2; cand[tid][3] = y2;
        cand[tid][4] = (x2 - x1) * (y2 - y1);
    }
    if (tid < NT){
        const float* tb = tboxG + ((size_t)s * NT + tid) * 4;
        float cx = fminf(fmaxf(tb[0], 0.f), 1.f);
        float cy = fminf(fmaxf(tb[1], 0.f), 1.f);
        float w  = fminf(fmaxf(tb[2], 0.f), 1.f);
        float h  = fminf(fmaxf(tb[3], 0.f), 1.f);
        tWH[tid][0] = cx; tWH[tid][1] = cy; tWH[tid][2] = w; tWH[tid][3] = h;
        float hw = w * 0.5f, hh = h * 0.5f;
        float x1 = cx - hw, y1 = cy - hh, x2 = cx + hw, y2 = cy + hh;
        tXY[tid][0] = x1; tXY[tid][1] = y1; tXY[tid][2] = x2; tXY[tid][3] = y2;
        tXY[tid][4] = (x2 - x1) * (y2 - y1);
        int c = tclsG[(size_t)s * NT + tid];
        tCl[tid] = min(max(c, 0), NC - 1);
    }
    __syncthreads();

    if (tid < NT){
        float tx1 = tXY[tid][0], ty1 = tXY[tid][1], tx2 = tXY[tid][2], ty2 = tXY[tid][3];
        float ta  = tXY[tid][4];
        float best = -1.0f; int bi = 0;
        for (int i = 0; i < KTOP; ++i){
            float iw = fminf(cand[i][2], tx2) - fmaxf(cand[i][0], tx1);
            iw = fmaxf(iw, 0.0f);
            float ih = fminf(cand[i][3], ty2) - fmaxf(cand[i][1], ty1);
            ih = fmaxf(ih, 0.0f);
            float inter = iw * ih;
            float uni = cand[i][4] + ta - inter;
            float iou = (uni > 0.0f) ? (inter / uni) : 0.0f;
            if (iou > best){ best = iou; bi = i; }
        }
        chosenA[tid] = sIdx[bi];
    }
    __syncthreads();

    if (tid < NT){
        int a = chosenA[tid];
        bool last = true;
        for (int j2 = tid + 1; j2 < NT; ++j2) if (chosenA[j2] == a) last = false;
        float corr = 0.f, clsv = 0.f, boxv = 0.f;
        if (last){
            const float* row = p_s + a * NF;
            float o = row[4];
            float spo = sp_f(o);
            corr = 2.0f * (spo - o) - 0.5f * spo;
            unsigned mask = 0;
            for (int j2 = 0; j2 < NT; ++j2)
                if (chosenA[j2] == a) mask |= (1u << tCl[j2]);
            const float smooth_neg = (float)(0.05 / 3.0);
            for (int c = 0; c < NC; ++c){
                float x = row[5 + c];
                float t = ((mask >> c) & 1u) ? 0.95f : smooth_neg;
                clsv += sp_f(x) - x * t;
            }
            for (int c = 0; c < 4; ++c){
                float p = sig_f(row[c]);
                float d = fabsf(p - tWH[tid][c]);
                boxv += (d < 0.1f) ? (0.5f * d * d / 0.1f) : (d - 0.05f);
            }
        }
        lastJ[tid] = last ? 1 : 0;
        corrJ[tid] = corr; clsJ[tid] = clsv; boxJ[tid] = boxv;
    }
    __syncthreads();

    if (tid == 0){
        double corrS = 0, clsS = 0, boxS = 0; int np = 0;
        for (int j = 0; j < NT; ++j){
            if (lastJ[j]){ np++; corrS += corrJ[j]; clsS += clsJ[j]; boxS += boxJ[j]; }
        }
        float obj_l = (float)((0.5 * s_spsum + corrS) / (double)AP);
        float cls_l = (np > 0) ? (float)(clsS / ((double)np * NC)) : 0.f;
        float box_l = (np > 0) ? (float)(boxS / ((double)np * 4) * 2.0) : 0.f;
        atomicAdd(&out[1], box_l);
        atomicAdd(&out[2], cls_l);
        atomicAdd(&out[3], obj_l);
        atomicAdd(&out[0], box_l + cls_l + obj_l);
    }
}

// ============================ LAUNCH ========================================

static inline size_t align256(size_t x){ return (x + 255) & ~(size_t)255; }

extern "C" void kernel_launch(void* const* d_in, const int* in_sizes, int n_in,
                              void* d_out, int out_size, void* d_ws, size_t ws_size,
                              hipStream_t stream) {
    const float* pred = (const float*)d_in[0];
    const float* tbox = (const float*)d_in[1];
    const int*   tcls = (const int*)d_in[2];
    float* out = (float*)d_out;

    // ws layout — every byte used is fully rewritten each call (no zeroing)
    const size_t oCnt   = 0;
    const size_t oPart  = align256(oCnt + (size_t)NBATCH * NBLKA * sizeof(int));
    const size_t oCKey  = align256(oPart + (size_t)NBATCH * NBLKA * sizeof(double));
    const size_t oCIdx  = align256(oCKey + (size_t)NBATCH * NBLKA * LCAP * sizeof(unsigned));
    const size_t oLoss  = align256(oCIdx + (size_t)NBATCH * NBLKA * LCAP * sizeof(int));
    const size_t need   = oLoss + (size_t)NBATCH * 4 * sizeof(float);
    const size_t keysB  = (size_t)NBATCH * AP * sizeof(unsigned);

    if (ws_size >= need){
        char* ws = (char*)d_ws;
        int*      candCnt = (int*)     (ws + oCnt);
        double*   parts   = (double*)  (ws + oPart);
        unsigned* candKey = (unsigned*)(ws + oCKey);
        int*      candIdx = (int*)     (ws + oCIdx);
        float*    lossP   = (float*)   (ws + oLoss);

        dim3 gwA(NBLKA, NBATCH);
        kA_scan<<<gwA, 256, 0, stream>>>(pred, parts, candKey, candIdx, candCnt);
        kB_finish<<<NBATCH, 1024, 0, stream>>>(pred, tbox, tcls, candKey, candIdx,
                                               candCnt, parts, lossP);
        k5_reduce<<<1, 64, 0, stream>>>(lossP, out);
    } else {
        hipMemsetAsync(d_out, 0, (size_t)out_size * sizeof(float), stream);
        unsigned* keys = (ws_size >= keysB) ? (unsigned*)d_ws : nullptr;
        if (keys){
            dim3 grid((AP + 255) / 256, NBATCH);
            build_keys_kernel<<<grid, 256, 0, stream>>>(pred, keys);
        }
        loss_kernel_full<<<NBATCH, 1024, 0, stream>>>(pred, keys, tbox, tcls, out);
    }
}

// Round 13
// 57.880 us; speedup vs baseline: 1.0414x; 1.0414x over previous
//
#include <hip/hip_runtime.h>
#include <math.h>

#define NBATCH 32
#define AP     75600   // anchors per sample = 25200*27/9
#define NF     9       // 4 box + 1 obj + 4 cls
#define KTOP   300
#define NT     50
#define NC     4
#define NBLKA  40      // wide blocks per sample (kA) — R9-measured best shape
#define LCAP   512     // kA per-block candidate slots (expect ~43/block)
#define CCAPL  3072    // kB LDS candidate capacity (expect ~1723)
#define MCAP   384     // member (top-300) capacity
#define EQCAP  1024    // ==T tie list capacity
#define PREFK  0xC0000000u   // fkey(2.0f): conservative prefilter threshold

__device__ __forceinline__ float sp_f(float x){           // jax.nn.softplus
    return fmaxf(x, 0.0f) + log1pf(expf(-fabsf(x)));
}
__device__ __forceinline__ float sig_f(float x){
    return 1.0f / (1.0f + expf(-x));
}
// monotone float->uint key (descending float order == descending uint order)
__device__ __forceinline__ unsigned fkey(float x){
    unsigned u = __float_as_uint(x);
    return (u & 0x80000000u) ? ~u : (u | 0x80000000u);
}
__device__ __forceinline__ float kinv(unsigned k){
    unsigned u = (k & 0x80000000u) ? (k & 0x7FFFFFFFu) : ~k;
    return __uint_as_float(u);
}

// ============================ FAST PATH (2 kernels) =========================

// kA: EXACTLY the R9 shape (51.2 us total — best measured). Grid-stride scan,
// softplus partials + prefilter compact into per-block slots. Plain stores,
// no zeroing, no global atomics. Also resets kB's ticket (runs before kB).
__global__ __launch_bounds__(256) void kA_scan(
    const float* __restrict__ pred, double* __restrict__ partials,
    unsigned* __restrict__ candKey, int* __restrict__ candIdx,
    int* __restrict__ candCnt, unsigned* __restrict__ ticket)
{
    const int s   = blockIdx.y;
    const int blk = blockIdx.x;
    const int tid = threadIdx.x;
    __shared__ unsigned bKey[LCAP];
    __shared__ int      bIdx[LCAP];
    __shared__ int      lcnt;
    __shared__ double   wsum[4];
    if (tid == 0) lcnt = 0;
    if (s == 0 && blk == 0 && tid == 1) *ticket = 0u;   // safe: kB runs after kA
    __syncthreads();

    const float* p_s = pred + (size_t)s * (AP*NF);
    double acc = 0.0;
    for (int i = blk*256 + tid; i < AP; i += NBLKA*256){
        float o = p_s[(size_t)i*NF + 4];
        acc += (double)sp_f(o);
        unsigned ky = fkey(o);
        if (ky >= PREFK){
            int p = atomicAdd(&lcnt, 1);          // LDS atomic, ~43 per block
            if (p < LCAP){ bKey[p] = ky; bIdx[p] = i; }
        }
    }
    for (int off = 32; off > 0; off >>= 1) acc += __shfl_down(acc, off);
    if ((tid & 63) == 0) wsum[tid >> 6] = acc;
    __syncthreads();
    if (tid == 0){
        partials[s*NBLKA + blk] = wsum[0] + wsum[1] + wsum[2] + wsum[3];
        candCnt[s*NBLKA + blk] = lcnt;            // raw (overflow detector)
    }
    const int n = min(lcnt, LCAP);
    unsigned* gk = candKey + ((size_t)s*NBLKA + blk) * LCAP;
    int*      gi = candIdx + ((size_t)s*NBLKA + blk) * LCAP;
    for (int i = tid; i < n; i += 256){ gk[i] = bKey[i]; gi[i] = bIdx[i]; }
}

// wave-parallel descending find-bin over ngroups*64 bins:
// find b with above(b) < need <= above(b)+hist[b]; above = sum of bins > b.
__device__ __forceinline__ void find_bin_wp(
    const unsigned* hist, int ngroups, unsigned need,
    unsigned* sGS, unsigned* sBin, unsigned* sAbove, int tid)
{
    const int wv = tid >> 6, ln = tid & 63;
    for (int g = wv; g < ngroups; g += 16){
        unsigned v = hist[g*64 + ln];
        #pragma unroll
        for (int off = 32; off > 0; off >>= 1){
            unsigned t = __shfl_down(v, off);
            if (ln + off < 64) v += t;
        }
        if (ln == 0) sGS[g] = v;
    }
    __syncthreads();
    if (wv == 0){
        unsigned gsv = (ln < ngroups) ? sGS[ln] : 0u;
        unsigned inc = gsv;                       // suffix-inclusive over groups
        #pragma unroll
        for (int off = 1; off < 64; off <<= 1){
            unsigned t = __shfl_down(inc, off);
            if (ln + off < 64) inc += t;
        }
        unsigned excl = inc - gsv;                // groups strictly above
        bool hit = (ln < ngroups) && (excl < need) && (need <= inc);
        unsigned long long mb = __ballot(hit);
        int gstar = __ffsll(mb) - 1;              // unique crossing group
        unsigned exG = __shfl(excl, gstar);
        unsigned y = hist[gstar*64 + ln];
        unsigned yinc = y;                        // suffix-inclusive within group
        #pragma unroll
        for (int off = 1; off < 64; off <<= 1){
            unsigned t = __shfl_down(yinc, off);
            if (ln + off < 64) yinc += t;
        }
        unsigned above = exG + (yinc - y);
        bool hit2 = (above < need) && (need <= above + y);
        mb = __ballot(hit2);
        int bl = __ffsll(mb) - 1;
        unsigned ab = __shfl(above, bl);
        if (ln == 0){ *sBin = (unsigned)(gstar*64 + bl); *sAbove = ab; }
    }
    __syncthreads();
}

// kB: per sample — wave-scan block counts, gather ~1723 candidates into LDS,
// 3-level radix select of exact top-300, IoU argmax, losses; LAST block
// (device ticket, R7-validated pattern) does the deterministic final reduce.
// Exact fallback: stream pred directly if prefilter coverage fails.
__global__ __launch_bounds__(1024) void kB_finish(
    const float* __restrict__ pred,
    const float* __restrict__ tboxG,
    const int*   __restrict__ tclsG,
    const unsigned* __restrict__ candKeyG, const int* __restrict__ candIdxG,
    const int* __restrict__ candCnt,
    const double* __restrict__ partials,
    float* __restrict__ lossPart, unsigned* __restrict__ ticket,
    float* __restrict__ out)
{
    const int s   = blockIdx.x;
    const int tid = threadIdx.x;
    const int wv  = tid >> 6;
    const int ln  = tid & 63;
    const float* p_s = pred + (size_t)s * (AP*NF);

    __shared__ unsigned cKey[CCAPL];
    __shared__ int      cIdx[CCAPL];
    __shared__ unsigned hist[2048];
    __shared__ unsigned sGS[32];
    __shared__ unsigned sB1, sA1, sB2, sA2, sB3, sA3;
    __shared__ int      bOff[NBLKA + 1];
    __shared__ int      sOk;
    __shared__ int      eqList[EQCAP];
    __shared__ int      eqCnt, mCnt;
    __shared__ unsigned mKey[MCAP];
    __shared__ int      mIdx[MCAP];
    __shared__ float    mB[5][MCAP];     // x1,y1,x2,y2,area
    __shared__ float    tXY[NT][5];
    __shared__ float    tWH[NT][4];
    __shared__ int      tCl[NT];
    __shared__ int      chosenA[NT];
    __shared__ float    corrJ[NT], clsJ[NT], boxJ[NT];
    __shared__ int      lastJ[NT];
    __shared__ double   s_spsum;
    __shared__ int      sTicket;

    // P0: wave-0 parallel scan of block counts; wave-15 reduces softplus
    if (tid == 0){ eqCnt = 0; mCnt = 0; }
    if (wv == 0){
        int c  = (ln < NBLKA) ? candCnt[s*NBLKA + ln] : 0;
        int of = (c > LCAP) ? 1 : 0;
        int cc = min(c, LCAP);
        int inc = cc;
        #pragma unroll
        for (int off = 1; off < 64; off <<= 1){
            int t = __shfl_up(inc, off);
            if (ln >= off) inc += t;
        }
        if (ln < NBLKA) bOff[ln + 1] = inc;
        unsigned long long anyof = __ballot(of != 0);
        if (ln == 0) bOff[0] = 0;
        if (ln == NBLKA - 1)
            sOk = (anyof == 0ull && inc >= KTOP && inc <= CCAPL) ? 1 : 0;
    }
    if (wv == 15){
        double a = (ln < NBLKA) ? partials[s*NBLKA + ln] : 0.0;
        for (int off = 32; off > 0; off >>= 1) a += __shfl_down(a, off);
        if (ln == 0) s_spsum = a;
    }
    __syncthreads();
    const bool fast = (sOk != 0);
    const int  n    = fast ? bOff[NBLKA] : 0;

    // P0b: gather candidates into LDS (fast path)
    if (fast){
        for (int b = wv; b < NBLKA; b += 16){
            const int c = min(candCnt[s*NBLKA + b], LCAP);
            const int o = bOff[b];
            const unsigned* gk = candKeyG + ((size_t)s*NBLKA + b) * LCAP;
            const int*      gi = candIdxG + ((size_t)s*NBLKA + b) * LCAP;
            for (int i = ln; i < c; i += 64){ cKey[o+i] = gk[i]; cIdx[o+i] = gi[i]; }
        }
    }
    // P1: level-1 histogram (top 11 bits)
    for (int i = tid; i < 2048; i += 1024) hist[i] = 0;
    __syncthreads();
    if (fast){
        for (int i = tid; i < n; i += 1024) atomicAdd(&hist[cKey[i] >> 21], 1u);
    } else {
        for (int i = tid; i < AP; i += 1024)
            atomicAdd(&hist[fkey(p_s[(size_t)i*NF + 4]) >> 21], 1u);
    }
    __syncthreads();
    find_bin_wp(hist, 32, KTOP, sGS, &sB1, &sA1, tid);
    const unsigned b1 = sB1, ab1 = sA1;
    const unsigned need2 = KTOP - ab1;

    // P2: level-2 histogram (bits 20..10) within bin b1
    for (int i = tid; i < 2048; i += 1024) hist[i] = 0;
    __syncthreads();
    if (fast){
        for (int i = tid; i < n; i += 1024){
            unsigned ky = cKey[i];
            if ((ky >> 21) == b1) atomicAdd(&hist[(ky >> 10) & 0x7FFu], 1u);
        }
    } else {
        for (int i = tid; i < AP; i += 1024){
            unsigned ky = fkey(p_s[(size_t)i*NF + 4]);
            if ((ky >> 21) == b1) atomicAdd(&hist[(ky >> 10) & 0x7FFu], 1u);
        }
    }
    __syncthreads();
    find_bin_wp(hist, 32, need2, sGS, &sB2, &sA2, tid);
    const unsigned b2 = sB2, ab2 = sA2;
    const unsigned need3 = need2 - ab2;
    const unsigned pref  = (b1 << 11) | b2;

    // P3: level-3 histogram (bits 9..0) within prefix
    if (tid < 1024) hist[tid] = 0;
    __syncthreads();
    if (fast){
        for (int i = tid; i < n; i += 1024){
            unsigned ky = cKey[i];
            if ((ky >> 10) == pref) atomicAdd(&hist[ky & 0x3FFu], 1u);
        }
    } else {
        for (int i = tid; i < AP; i += 1024){
            unsigned ky = fkey(p_s[(size_t)i*NF + 4]);
            if ((ky >> 10) == pref) atomicAdd(&hist[ky & 0x3FFu], 1u);
        }
    }
    __syncthreads();
    find_bin_wp(hist, 16, need3, sGS, &sB3, &sA3, tid);
    const unsigned b3 = sB3, ab3 = sA3;
    const unsigned needEq = need3 - ab3;
    const unsigned T = (b1 << 21) | (b2 << 10) | b3;

    // P4: collect ==T ties
    if (fast){
        for (int i = tid; i < n; i += 1024){
            if (cKey[i] == T){
                int p = atomicAdd(&eqCnt, 1);
                if (p < EQCAP) eqList[p] = cIdx[i];
            }
        }
    } else {
        for (int i = tid; i < AP; i += 1024){
            if (fkey(p_s[(size_t)i*NF + 4]) == T){
                int p = atomicAdd(&eqCnt, 1);
                if (p < EQCAP) eqList[p] = i;
            }
        }
    }
    __syncthreads();
    const int ne = min(eqCnt, EQCAP);

    // P5: membership (exact top-300 set) + ballot compaction
    const int dom = fast ? n : AP;
    for (int base = wv*64; base < dom; base += 1024){
        int i = base + ln;
        bool mflag = false; unsigned ky = 0; int ix = 0;
        if (i < dom){
            if (fast){ ky = cKey[i]; ix = cIdx[i]; }
            else     { ky = fkey(p_s[(size_t)i*NF + 4]); ix = i; }
            if (ky > T) mflag = true;
            else if (ky == T){
                int r = 0;
                for (int j = 0; j < ne; ++j) r += (eqList[j] < ix) ? 1 : 0;
                mflag = ((unsigned)r < needEq);   // lowest-index ties, lax.top_k order
            }
        }
        unsigned long long msk = __ballot(mflag);
        int bpos = 0;
        if (ln == 0 && msk) bpos = atomicAdd(&mCnt, (int)__popcll(msk));
        bpos = __shfl(bpos, 0);
        if (mflag){
            int pos = bpos + (int)__popcll(msk & ((1ull << ln) - 1ull));
            if (pos < MCAP){ mKey[pos] = ky; mIdx[pos] = ix; }
        }
    }
    __syncthreads();
    const int kM = min(mCnt, MCAP);   // == 300 by construction

    // P6: boxes for members (pred rows are L3-resident after kA) + targets
    for (int m = tid; m < kM; m += 1024){
        const float* row = p_s + (size_t)mIdx[m] * NF;
        float bx = sig_f(row[0]), by = sig_f(row[1]);
        float bw = sig_f(row[2]), bh = sig_f(row[3]);
        float hw = bw * 0.5f, hh = bh * 0.5f;
        float x1 = bx - hw, y1 = by - hh, x2 = bx + hw, y2 = by + hh;
        mB[0][m] = x1; mB[1][m] = y1; mB[2][m] = x2; mB[3][m] = y2;
        mB[4][m] = (x2 - x1) * (y2 - y1);
    }
    if (tid >= 512 && tid < 512 + NT){
        int t = tid - 512;
        const float* tb = tboxG + ((size_t)s * NT + t) * 4;
        float cx = fminf(fmaxf(tb[0], 0.f), 1.f);
        float cy = fminf(fmaxf(tb[1], 0.f), 1.f);
        float w  = fminf(fmaxf(tb[2], 0.f), 1.f);
        float h  = fminf(fmaxf(tb[3], 0.f), 1.f);
        tWH[t][0] = cx; tWH[t][1] = cy; tWH[t][2] = w; tWH[t][3] = h;
        float hw = w * 0.5f, hh = h * 0.5f;
        float x1 = cx - hw, y1 = cy - hh, x2 = cx + hw, y2 = cy + hh;
        tXY[t][0] = x1; tXY[t][1] = y1; tXY[t][2] = x2; tXY[t][3] = y2;
        tXY[t][4] = (x2 - x1) * (y2 - y1);
        int c = tclsG[(size_t)s * NT + t];
        tCl[t] = min(max(c, 0), NC - 1);
    }
    __syncthreads();

    // P7: per-target argmax over the SET by (iou desc, key desc, idx asc)
    for (int t = wv; t < NT; t += 16){
        float tx1 = tXY[t][0], ty1 = tXY[t][1], tx2 = tXY[t][2], ty2 = tXY[t][3];
        float ta  = tXY[t][4];
        float    bIou = -1.0f; unsigned bKy = 0; int bIx = 0x7FFFFFFF;
        for (int m = ln; m < kM; m += 64){
            float iw = fminf(mB[2][m], tx2) - fmaxf(mB[0][m], tx1);
            iw = fmaxf(iw, 0.0f);
            float ih = fminf(mB[3][m], ty2) - fmaxf(mB[1][m], ty1);
            ih = fmaxf(ih, 0.0f);
            float inter = iw * ih;
            float uni = mB[4][m] + ta - inter;
            float iou = (uni > 0.0f) ? (inter / uni) : 0.0f;
            unsigned ky = mKey[m]; int ix = mIdx[m];
            if (iou > bIou || (iou == bIou && (ky > bKy || (ky == bKy && ix < bIx)))){
                bIou = iou; bKy = ky; bIx = ix;
            }
        }
        #pragma unroll
        for (int off = 32; off > 0; off >>= 1){
            float    oI = __shfl_down(bIou, off);
            unsigned oK = __shfl_down(bKy,  off);
            int      oX = __shfl_down(bIx,  off);
            bool take = (ln + off < 64) &&
                        (oI > bIou || (oI == bIou && (oK > bKy || (oK == bKy && oX < bIx))));
            if (take){ bIou = oI; bKy = oK; bIx = oX; }
        }
        if (ln == 0) chosenA[t] = bIx;
    }
    __syncthreads();

    // P8: per-target contributions; duplicates: last j wins rows, cls classes union
    if (tid < NT){
        int a = chosenA[tid];
        bool last = true;
        for (int j2 = tid + 1; j2 < NT; ++j2) if (chosenA[j2] == a) last = false;
        float corr = 0.f, clsv = 0.f, boxv = 0.f;
        if (last){
            const float* row = p_s + (size_t)a * NF;
            float o = row[4];
            float spo = sp_f(o);
            corr = 2.0f * (spo - o) - 0.5f * spo;   // replace 0.5*sp with 2*(sp-x)
            unsigned mask = 0;
            for (int j2 = 0; j2 < NT; ++j2)
                if (chosenA[j2] == a) mask |= (1u << tCl[j2]);
            const float smooth_neg = (float)(0.05 / 3.0);
            for (int c = 0; c < NC; ++c){
                float x = row[5 + c];
                float t = ((mask >> c) & 1u) ? 0.95f : smooth_neg;
                clsv += sp_f(x) - x * t;
            }
            for (int c = 0; c < 4; ++c){
                float p = sig_f(row[c]);
                float d = fabsf(p - tWH[tid][c]);
                boxv += (d < 0.1f) ? (0.5f * d * d / 0.1f) : (d - 0.05f);
            }
        }
        lastJ[tid] = last ? 1 : 0;
        corrJ[tid] = corr; clsJ[tid] = clsv; boxJ[tid] = boxv;
    }
    __syncthreads();

    if (tid == 0){
        double corrS = 0, clsS = 0, boxS = 0; int np = 0;
        for (int j = 0; j < NT; ++j){
            if (lastJ[j]){ np++; corrS += corrJ[j]; clsS += clsJ[j]; boxS += boxJ[j]; }
        }
        float obj_l = (float)((0.5 * s_spsum + corrS) / (double)AP);
        float cls_l = (np > 0) ? (float)(clsS / ((double)np * NC)) : 0.f;
        float box_l = (np > 0) ? (float)(boxS / ((double)np * 4) * 2.0) : 0.f;
        lossPart[s*4 + 0] = box_l;
        lossPart[s*4 + 1] = cls_l;
        lossPart[s*4 + 2] = obj_l;
    }
    __syncthreads();

    // P9: last-block deterministic reduce (ticket zeroed by kA; R7-validated)
    if (tid == 0){
        __threadfence();                             // publish lossPart
        sTicket = (int)atomicAdd(ticket, 1u);        // device-scope
    }
    __syncthreads();
    if (sTicket == NBATCH - 1 && tid == 0){
        __threadfence();                             // acquire
        volatile const float* lp = lossPart;
        double b = 0, c = 0, o = 0;
        for (int s2 = 0; s2 < NBATCH; ++s2){
            b += (double)lp[s2*4 + 0];
            c += (double)lp[s2*4 + 1];
            o += (double)lp[s2*4 + 2];
        }
        out[1] = (float)b; out[2] = (float)c; out[3] = (float)o;
        out[0] = (float)(b + c + o);
    }
}

// ============================ FALLBACK (round-1) ============================

__device__ __forceinline__ unsigned load_key(const unsigned* k_s, const float* p_s, int i){
    return k_s ? k_s[i] : fkey(p_s[i*NF + 4]);
}

__global__ void build_keys_kernel(const float* __restrict__ pred, unsigned* __restrict__ keys){
    int s = blockIdx.y;
    int a = blockIdx.x * 256 + threadIdx.x;
    if (a < AP){
        float o = pred[(size_t)s * (AP*NF) + (size_t)a * NF + 4];
        keys[s * AP + a] = fkey(o);
    }
}

__device__ void find_bin(unsigned* hist, unsigned* ssup, int* sbin, unsigned* sabove,
                         unsigned need, int tid){
    if (tid < 32){
        unsigned a2 = 0;
        for (int i = 0; i < 64; ++i) a2 += hist[tid*64 + i];
        ssup[tid] = a2;
    }
    __syncthreads();
    if (tid == 0){
        unsigned a2 = 0; int g = 31;
        for (; g > 0; --g){ if (a2 + ssup[g] >= need) break; a2 += ssup[g]; }
        int b = g*64 + 63;
        for (;;){ unsigned h = hist[b]; if (a2 + h >= need || b == g*64) break; a2 += h; --b; }
        *sbin = b; *sabove = a2;
    }
    __syncthreads();
}

__global__ __launch_bounds__(1024) void loss_kernel_full(
    const float* __restrict__ pred,
    const unsigned* __restrict__ keysG,
    const float* __restrict__ tboxG,
    const int*   __restrict__ tclsG,
    float* __restrict__ out)
{
    const int s   = blockIdx.x;
    const int tid = threadIdx.x;
    const float*    p_s = pred + (size_t)s * (AP*NF);
    const unsigned* k_s = keysG ? (keysG + s * AP) : nullptr;

    __shared__ unsigned hist[2048];
    __shared__ unsigned ssup[32];
    __shared__ int sbin; __shared__ unsigned sabove;
    __shared__ double wsum[16];
    __shared__ double s_spsum;
    __shared__ unsigned tkKey[KTOP]; __shared__ int tkIdx[KTOP];
    __shared__ int eqIdx[2048];
    __shared__ int nGt, nEq;
    __shared__ int sIdx[KTOP];
    __shared__ float cand[KTOP][5];
    __shared__ float tXY[NT][5];
    __shared__ float tWH[NT][4];
    __shared__ int   tCl[NT];
    __shared__ int   chosenA[NT];
    __shared__ float corrJ[NT], clsJ[NT], boxJ[NT];
    __shared__ int   lastJ[NT];

    for (int i = tid; i < 2048; i += 1024) hist[i] = 0;
    if (tid == 0){ nGt = 0; nEq = 0; }
    __syncthreads();
    double acc = 0.0;
    for (int i = tid; i < AP; i += 1024){
        unsigned ky = load_key(k_s, p_s, i);
        atomicAdd(&hist[ky >> 21], 1u);
        acc += (double)sp_f(kinv(ky));
    }
    for (int off = 32; off > 0; off >>= 1) acc += __shfl_down(acc, off);
    if ((tid & 63) == 0) wsum[tid >> 6] = acc;
    __syncthreads();
    if (tid == 0){
        double t = 0.0;
        for (int w = 0; w < 16; ++w) t += wsum[w];
        s_spsum = t;
    }
    __syncthreads();

    find_bin(hist, ssup, &sbin, &sabove, KTOP, tid);
    const int b1 = sbin; const unsigned above1 = sabove;
    const unsigned need2 = KTOP - above1;
    __syncthreads();

    for (int i = tid; i < 2048; i += 1024) hist[i] = 0;
    __syncthreads();
    for (int i = tid; i < AP; i += 1024){
        unsigned ky = load_key(k_s, p_s, i);
        if ((int)(ky >> 21) == b1) atomicAdd(&hist[(ky >> 10) & 0x7FFu], 1u);
    }
    __syncthreads();
    find_bin(hist, ssup, &sbin, &sabove, need2, tid);
    const int b2 = sbin; const unsigned above2 = sabove;
    const unsigned need3 = need2 - above2;
    const unsigned pref  = ((unsigned)b1 << 11) | (unsigned)b2;
    __syncthreads();

    for (int i = tid; i < 2048; i += 1024) hist[i] = 0;
    __syncthreads();
    for (int i = tid; i < AP; i += 1024){
        unsigned ky = load_key(k_s, p_s, i);
        if ((ky >> 10) == pref) atomicAdd(&hist[ky & 0x3FFu], 1u);
    }
    __syncthreads();
    find_bin(hist, ssup, &sbin, &sabove, need3, tid);
    const int b3 = sbin; const unsigned above3 = sabove;
    const unsigned needEq = need3 - above3;
    const unsigned T      = ((unsigned)b1 << 21) | ((unsigned)b2 << 10) | (unsigned)b3;
    const unsigned cntGt  = above1 + above2 + above3;
    __syncthreads();

    for (int i = tid; i < AP; i += 1024){
        unsigned ky = load_key(k_s, p_s, i);
        if (ky > T){
            int p = atomicAdd(&nGt, 1);
            if (p < KTOP){ tkKey[p] = ky; tkIdx[p] = i; }
        } else if (ky == T){
            int p = atomicAdd(&nEq, 1);
            if (p < 2048) eqIdx[p] = i;
        }
    }
    __syncthreads();
    {
        int ne = min(nEq, 2048);
        for (int t = tid; t < ne; t += 1024){
            int mine = eqIdx[t]; int r = 0;
            for (int j = 0; j < ne; ++j) r += (eqIdx[j] < mine) ? 1 : 0;
            if ((unsigned)r < needEq){
                int p = (int)cntGt + r;
                if (p < KTOP){ tkKey[p] = T; tkIdx[p] = mine; }
            }
        }
    }
    __syncthreads();

    if (tid < KTOP){
        unsigned myk = tkKey[tid]; int myi = tkIdx[tid];
        int r = 0;
        for (int j = 0; j < KTOP; ++j){
            unsigned kj = tkKey[j]; int ij = tkIdx[j];
            r += (kj > myk || (kj == myk && ij < myi)) ? 1 : 0;
        }
        sIdx[r] = myi;
    }
    __syncthreads();

    if (tid < KTOP){
        int a = sIdx[tid];
        const float* row = p_s + a * NF;
        float bx = sig_f(row[0]), by = sig_f(row[1]);
        float bw = sig_f(row[2]), bh = sig_f(row[3]);
        float hw = bw * 0.5f, hh = bh * 0.5f;
        float x1 = bx - hw, y1 = by - hh, x2 = bx + hw, y2 = by + hh;
        cand[tid][0] = x1; cand[tid][1] = y1; cand[tid][2] = x2; cand[tid][3] = y2;
        cand[tid][4] = (x2 - x1) * (y2 - y1);
    }
    if (tid < NT){
        const float* tb = tboxG + ((size_t)s * NT + tid) * 4;
        float cx = fminf(fmaxf(tb[0], 0.f), 1.f);
        float cy = fminf(fmaxf(tb[1], 0.f), 1.f);
        float w  = fminf(fmaxf(tb[2], 0.f), 1.f);
        float h  = fminf(fmaxf(tb[3], 0.f), 1.f);
        tWH[tid][0] = cx; tWH[tid][1] = cy; tWH[tid][2] = w; tWH[tid][3] = h;
        float hw = w * 0.5f, hh = h * 0.5f;
        float x1 = cx - hw, y1 = cy - hh, x2 = cx + hw, y2 = cy + hh;
        tXY[tid][0] = x1; tXY[tid][1] = y1; tXY[tid][2] = x2; tXY[tid][3] = y2;
        tXY[tid][4] = (x2 - x1) * (y2 - y1);
        int c = tclsG[(size_t)s * NT + tid];
        tCl[tid] = min(max(c, 0), NC - 1);
    }
    __syncthreads();

    if (tid < NT){
        float tx1 = tXY[tid][0], ty1 = tXY[tid][1], tx2 = tXY[tid][2], ty2 = tXY[tid][3];
        float ta  = tXY[tid][4];
        float best = -1.0f; int bi = 0;
        for (int i = 0; i < KTOP; ++i){
            float iw = fminf(cand[i][2], tx2) - fmaxf(cand[i][0], tx1);
            iw = fmaxf(iw, 0.0f);
            float ih = fminf(cand[i][3], ty2) - fmaxf(cand[i][1], ty1);
            ih = fmaxf(ih, 0.0f);
            float inter = iw * ih;
            float uni = cand[i][4] + ta - inter;
            float iou = (uni > 0.0f) ? (inter / uni) : 0.0f;
            if (iou > best){ best = iou; bi = i; }
        }
        chosenA[tid] = sIdx[bi];
    }
    __syncthreads();

    if (tid < NT){
        int a = chosenA[tid];
        bool last = true;
        for (int j2 = tid + 1; j2 < NT; ++j2) if (chosenA[j2] == a) last = false;
        float corr = 0.f, clsv = 0.f, boxv = 0.f;
        if (last){
            const float* row = p_s + a * NF;
            float o = row[4];
            float spo = sp_f(o);
            corr = 2.0f * (spo - o) - 0.5f * spo;
            unsigned mask = 0;
            for (int j2 = 0; j2 < NT; ++j2)
                if (chosenA[j2] == a) mask |= (1u << tCl[j2]);
            const float smooth_neg = (float)(0.05 / 3.0);
            for (int c = 0; c < NC; ++c){
                float x = row[5 + c];
                float t = ((mask >> c) & 1u) ? 0.95f : smooth_neg;
                clsv += sp_f(x) - x * t;
            }
            for (int c = 0; c < 4; ++c){
                float p = sig_f(row[c]);
                float d = fabsf(p - tWH[tid][c]);
                boxv += (d < 0.1f) ? (0.5f * d * d / 0.1f) : (d - 0.05f);
            }
        }
        lastJ[tid] = last ? 1 : 0;
        corrJ[tid] = corr; clsJ[tid] = clsv; boxJ[tid] = boxv;
    }
    __syncthreads();

    if (tid == 0){
        double corrS = 0, clsS = 0, boxS = 0; int np = 0;
        for (int j = 0; j < NT; ++j){
            if (lastJ[j]){ np++; corrS += corrJ[j]; clsS += clsJ[j]; boxS += boxJ[j]; }
        }
        float obj_l = (float)((0.5 * s_spsum + corrS) / (double)AP);
        float cls_l = (np > 0) ? (float)(clsS / ((double)np * NC)) : 0.f;
        float box_l = (np > 0) ? (float)(boxS / ((double)np * 4) * 2.0) : 0.f;
        atomicAdd(&out[1], box_l);
        atomicAdd(&out[2], cls_l);
        atomicAdd(&out[3], obj_l);
        atomicAdd(&out[0], box_l + cls_l + obj_l);
    }
}

// ============================ LAUNCH ========================================

static inline size_t align256(size_t x){ return (x + 255) & ~(size_t)255; }

extern "C" void kernel_launch(void* const* d_in, const int* in_sizes, int n_in,
                              void* d_out, int out_size, void* d_ws, size_t ws_size,
                              hipStream_t stream) {
    const float* pred = (const float*)d_in[0];
    const float* tbox = (const float*)d_in[1];
    const int*   tcls = (const int*)d_in[2];
    float* out = (float*)d_out;

    // ws layout — every byte used is fully rewritten each call (no zeroing;
    // ticket reset by kA before kB runs)
    const size_t oCnt   = 0;
    const size_t oPart  = align256(oCnt + (size_t)NBATCH * NBLKA * sizeof(int));
    const size_t oCKey  = align256(oPart + (size_t)NBATCH * NBLKA * sizeof(double));
    const size_t oCIdx  = align256(oCKey + (size_t)NBATCH * NBLKA * LCAP * sizeof(unsigned));
    const size_t oLoss  = align256(oCIdx + (size_t)NBATCH * NBLKA * LCAP * sizeof(int));
    const size_t oTick  = align256(oLoss + (size_t)NBATCH * 4 * sizeof(float));
    const size_t need   = oTick + 256;
    const size_t keysB  = (size_t)NBATCH * AP * sizeof(unsigned);

    if (ws_size >= need){
        char* ws = (char*)d_ws;
        int*      candCnt = (int*)     (ws + oCnt);
        double*   parts   = (double*)  (ws + oPart);
        unsigned* candKey = (unsigned*)(ws + oCKey);
        int*      candIdx = (int*)     (ws + oCIdx);
        float*    lossP   = (float*)   (ws + oLoss);
        unsigned* ticket  = (unsigned*)(ws + oTick);

        dim3 gwA(NBLKA, NBATCH);
        kA_scan<<<gwA, 256, 0, stream>>>(pred, parts, candKey, candIdx, candCnt, ticket);
        kB_finish<<<NBATCH, 1024, 0, stream>>>(pred, tbox, tcls, candKey, candIdx,
                                               candCnt, parts, lossP, ticket, out);
    } else {
        hipMemsetAsync(d_out, 0, (size_t)out_size * sizeof(float), stream);
        unsigned* keys = (ws_size >= keysB) ? (unsigned*)d_ws : nullptr;
        if (keys){
            dim3 grid((AP + 255) / 256, NBATCH);
            build_keys_kernel<<<grid, 256, 0, stream>>>(pred, keys);
        }
        loss_kernel_full<<<NBATCH, 1024, 0, stream>>>(pred, keys, tbox, tcls, out);
    }
}

// Round 14
// 50.212 us; speedup vs baseline: 1.2004x; 1.1527x over previous
//
#include <hip/hip_runtime.h>
#include <math.h>

#define NBATCH 32
#define AP     75600   // anchors per sample = 25200*27/9
#define NF     9       // 4 box + 1 obj + 4 cls
#define KTOP   300
#define NT     50
#define NC     4
#define NBLK1  40      // wide blocks per sample (kA) — R9-measured best shape
#define LCAP   512     // kA per-block candidate slots (expect ~43/block)
#define CCAPL  3072    // kB LDS candidate capacity (expect ~1723)
#define MCAP   384     // member (top-300) capacity
#define EQCAP  1024    // ==T tie list capacity
#define PREFK  0xC0000000u   // fkey(2.0f): conservative prefilter threshold

__device__ __forceinline__ float sp_f(float x){           // exact softplus (kB)
    return fmaxf(x, 0.0f) + log1pf(expf(-fabsf(x)));
}
// fast softplus for kA's 2.4M-element SUM only (native v_exp/v_log, ~6 instrs
// vs ~25 for libm). Absolute error <1e-6/elem -> <1e-5 on obj loss, vs 0.84
// threshold. Selection keys use raw bits (exact), so top-k is unaffected.
__device__ __forceinline__ float sp_fast(float x){
    return fmaxf(x, 0.0f) + __logf(1.0f + __expf(-fabsf(x)));
}
__device__ __forceinline__ float sig_f(float x){
    return 1.0f / (1.0f + expf(-x));
}
// monotone float->uint key (descending float order == descending uint order)
__device__ __forceinline__ unsigned fkey(float x){
    unsigned u = __float_as_uint(x);
    return (u & 0x80000000u) ? ~u : (u | 0x80000000u);
}
__device__ __forceinline__ float kinv(unsigned k){
    unsigned u = (k & 0x80000000u) ? (k & 0x7FFFFFFFu) : ~k;
    return __uint_as_float(u);
}

// ============================ FAST PATH (3 kernels, R9 structure) ===========

// kA: R9 shape (best measured), with fast softplus. Grid-stride scan,
// softplus partials + prefilter compact into per-block slots. Plain stores,
// no zeroing, no global atomics.
__global__ __launch_bounds__(256) void kA_scan(
    const float* __restrict__ pred, double* __restrict__ partials,
    unsigned* __restrict__ candKey, int* __restrict__ candIdx,
    int* __restrict__ candCnt)
{
    const int s   = blockIdx.y;
    const int blk = blockIdx.x;
    const int tid = threadIdx.x;
    __shared__ unsigned bKey[LCAP];
    __shared__ int      bIdx[LCAP];
    __shared__ int      lcnt;
    __shared__ double   wsum[4];
    if (tid == 0) lcnt = 0;
    __syncthreads();

    const float* p_s = pred + (size_t)s * (AP*NF);
    double acc = 0.0;
    for (int i = blk*256 + tid; i < AP; i += NBLK1*256){
        float o = p_s[(size_t)i*NF + 4];
        acc += (double)sp_fast(o);
        unsigned ky = fkey(o);
        if (ky >= PREFK){
            int p = atomicAdd(&lcnt, 1);          // LDS atomic, ~43 per block
            if (p < LCAP){ bKey[p] = ky; bIdx[p] = i; }
        }
    }
    for (int off = 32; off > 0; off >>= 1) acc += __shfl_down(acc, off);
    if ((tid & 63) == 0) wsum[tid >> 6] = acc;
    __syncthreads();
    if (tid == 0){
        partials[s*NBLK1 + blk] = wsum[0] + wsum[1] + wsum[2] + wsum[3];
        candCnt[s*NBLK1 + blk] = lcnt;            // raw (overflow detector)
    }
    const int n = min(lcnt, LCAP);
    unsigned* gk = candKey + ((size_t)s*NBLK1 + blk) * LCAP;
    int*      gi = candIdx + ((size_t)s*NBLK1 + blk) * LCAP;
    for (int i = tid; i < n; i += 256){ gk[i] = bKey[i]; gi[i] = bIdx[i]; }
}

// wave-parallel descending find-bin over ngroups*64 bins:
// find b with above(b) < need <= above(b)+hist[b]; above = sum of bins > b.
__device__ __forceinline__ void find_bin_wp(
    const unsigned* hist, int ngroups, unsigned need,
    unsigned* sGS, unsigned* sBin, unsigned* sAbove, int tid)
{
    const int wv = tid >> 6, ln = tid & 63;
    for (int g = wv; g < ngroups; g += 16){
        unsigned v = hist[g*64 + ln];
        #pragma unroll
        for (int off = 32; off > 0; off >>= 1){
            unsigned t = __shfl_down(v, off);
            if (ln + off < 64) v += t;
        }
        if (ln == 0) sGS[g] = v;
    }
    __syncthreads();
    if (wv == 0){
        unsigned gsv = (ln < ngroups) ? sGS[ln] : 0u;
        unsigned inc = gsv;                       // suffix-inclusive over groups
        #pragma unroll
        for (int off = 1; off < 64; off <<= 1){
            unsigned t = __shfl_down(inc, off);
            if (ln + off < 64) inc += t;
        }
        unsigned excl = inc - gsv;                // groups strictly above
        bool hit = (ln < ngroups) && (excl < need) && (need <= inc);
        unsigned long long mb = __ballot(hit);
        int gstar = __ffsll(mb) - 1;              // unique crossing group
        unsigned exG = __shfl(excl, gstar);
        unsigned y = hist[gstar*64 + ln];
        unsigned yinc = y;                        // suffix-inclusive within group
        #pragma unroll
        for (int off = 1; off < 64; off <<= 1){
            unsigned t = __shfl_down(yinc, off);
            if (ln + off < 64) yinc += t;
        }
        unsigned above = exG + (yinc - y);
        bool hit2 = (above < need) && (need <= above + y);
        mb = __ballot(hit2);
        int bl = __ffsll(mb) - 1;
        unsigned ab = __shfl(above, bl);
        if (ln == 0){ *sBin = (unsigned)(gstar*64 + bl); *sAbove = ab; }
    }
    __syncthreads();
}

// kB: per sample — gather per-block candidates into LDS (~1723, all >=2.0 in
// obj logit), 3-level radix select of the exact top-300 among them, IoU
// argmax, losses. Exact fallback: stream pred directly if coverage fails.
__global__ __launch_bounds__(1024) void kB_finish(
    const float* __restrict__ pred,
    const float* __restrict__ tboxG,
    const int*   __restrict__ tclsG,
    const unsigned* __restrict__ candKeyG, const int* __restrict__ candIdxG,
    const int* __restrict__ candCnt,
    const double* __restrict__ partials,
    float* __restrict__ lossPart)
{
    const int s   = blockIdx.x;
    const int tid = threadIdx.x;
    const int wv  = tid >> 6;
    const int ln  = tid & 63;
    const float* p_s = pred + (size_t)s * (AP*NF);

    __shared__ unsigned cKey[CCAPL];
    __shared__ int      cIdx[CCAPL];
    __shared__ unsigned hist[2048];
    __shared__ unsigned sGS[32];
    __shared__ unsigned sB1, sA1, sB2, sA2, sB3, sA3;
    __shared__ int      bOff[NBLK1 + 1];
    __shared__ int      sOk;
    __shared__ int      eqList[EQCAP];
    __shared__ int      eqCnt, mCnt;
    __shared__ unsigned mKey[MCAP];
    __shared__ int      mIdx[MCAP];
    __shared__ float    mB[5][MCAP];     // x1,y1,x2,y2,area
    __shared__ float    tXY[NT][5];
    __shared__ float    tWH[NT][4];
    __shared__ int      tCl[NT];
    __shared__ int      chosenA[NT];
    __shared__ float    corrJ[NT], clsJ[NT], boxJ[NT];
    __shared__ int      lastJ[NT];
    __shared__ double   s_spsum;

    // P0: prefix-sum block counts; validate fast-path coverage
    if (tid == 0){
        int o = 0; bool ok = true;
        for (int b = 0; b < NBLK1; ++b){
            int c = candCnt[s*NBLK1 + b];
            if (c > LCAP) ok = false;
            bOff[b] = o; o += min(c, LCAP);
        }
        bOff[NBLK1] = o;
        sOk = (ok && o >= KTOP && o <= CCAPL) ? 1 : 0;
        eqCnt = 0; mCnt = 0;
    }
    if (wv == 15){
        double a = (ln < NBLK1) ? partials[s*NBLK1 + ln] : 0.0;
        for (int off = 32; off > 0; off >>= 1) a += __shfl_down(a, off);
        if (ln == 0) s_spsum = a;
    }
    __syncthreads();
    const bool fast = (sOk != 0);
    const int  n    = fast ? bOff[NBLK1] : 0;

    // P0b: gather candidates into LDS (fast path)
    if (fast){
        for (int b = wv; b < NBLK1; b += 16){
            const int c = min(candCnt[s*NBLK1 + b], LCAP);
            const int o = bOff[b];
            const unsigned* gk = candKeyG + ((size_t)s*NBLK1 + b) * LCAP;
            const int*      gi = candIdxG + ((size_t)s*NBLK1 + b) * LCAP;
            for (int i = ln; i < c; i += 64){ cKey[o+i] = gk[i]; cIdx[o+i] = gi[i]; }
        }
    }
    // P1: level-1 histogram (top 11 bits)
    for (int i = tid; i < 2048; i += 1024) hist[i] = 0;
    __syncthreads();
    if (fast){
        for (int i = tid; i < n; i += 1024) atomicAdd(&hist[cKey[i] >> 21], 1u);
    } else {
        for (int i = tid; i < AP; i += 1024)
            atomicAdd(&hist[fkey(p_s[(size_t)i*NF + 4]) >> 21], 1u);
    }
    __syncthreads();
    find_bin_wp(hist, 32, KTOP, sGS, &sB1, &sA1, tid);
    const unsigned b1 = sB1, ab1 = sA1;
    const unsigned need2 = KTOP - ab1;

    // P2: level-2 histogram (bits 20..10) within bin b1
    for (int i = tid; i < 2048; i += 1024) hist[i] = 0;
    __syncthreads();
    if (fast){
        for (int i = tid; i < n; i += 1024){
            unsigned ky = cKey[i];
            if ((ky >> 21) == b1) atomicAdd(&hist[(ky >> 10) & 0x7FFu], 1u);
        }
    } else {
        for (int i = tid; i < AP; i += 1024){
            unsigned ky = fkey(p_s[(size_t)i*NF + 4]);
            if ((ky >> 21) == b1) atomicAdd(&hist[(ky >> 10) & 0x7FFu], 1u);
        }
    }
    __syncthreads();
    find_bin_wp(hist, 32, need2, sGS, &sB2, &sA2, tid);
    const unsigned b2 = sB2, ab2 = sA2;
    const unsigned need3 = need2 - ab2;
    const unsigned pref  = (b1 << 11) | b2;

    // P3: level-3 histogram (bits 9..0) within prefix
    if (tid < 1024) hist[tid] = 0;
    __syncthreads();
    if (fast){
        for (int i = tid; i < n; i += 1024){
            unsigned ky = cKey[i];
            if ((ky >> 10) == pref) atomicAdd(&hist[ky & 0x3FFu], 1u);
        }
    } else {
        for (int i = tid; i < AP; i += 1024){
            unsigned ky = fkey(p_s[(size_t)i*NF + 4]);
            if ((ky >> 10) == pref) atomicAdd(&hist[ky & 0x3FFu], 1u);
        }
    }
    __syncthreads();
    find_bin_wp(hist, 16, need3, sGS, &sB3, &sA3, tid);
    const unsigned b3 = sB3, ab3 = sA3;
    const unsigned needEq = need3 - ab3;
    const unsigned T = (b1 << 21) | (b2 << 10) | b3;

    // P4: collect ==T ties
    if (fast){
        for (int i = tid; i < n; i += 1024){
            if (cKey[i] == T){
                int p = atomicAdd(&eqCnt, 1);
                if (p < EQCAP) eqList[p] = cIdx[i];
            }
        }
    } else {
        for (int i = tid; i < AP; i += 1024){
            if (fkey(p_s[(size_t)i*NF + 4]) == T){
                int p = atomicAdd(&eqCnt, 1);
                if (p < EQCAP) eqList[p] = i;
            }
        }
    }
    __syncthreads();
    const int ne = min(eqCnt, EQCAP);

    // P5: membership (exact top-300 set) + ballot compaction
    const int dom = fast ? n : AP;
    for (int base = wv*64; base < dom; base += 1024){
        int i = base + ln;
        bool mflag = false; unsigned ky = 0; int ix = 0;
        if (i < dom){
            if (fast){ ky = cKey[i]; ix = cIdx[i]; }
            else     { ky = fkey(p_s[(size_t)i*NF + 4]); ix = i; }
            if (ky > T) mflag = true;
            else if (ky == T){
                int r = 0;
                for (int j = 0; j < ne; ++j) r += (eqList[j] < ix) ? 1 : 0;
                mflag = ((unsigned)r < needEq);   // lowest-index ties, lax.top_k order
            }
        }
        unsigned long long msk = __ballot(mflag);
        int bpos = 0;
        if (ln == 0 && msk) bpos = atomicAdd(&mCnt, (int)__popcll(msk));
        bpos = __shfl(bpos, 0);
        if (mflag){
            int pos = bpos + (int)__popcll(msk & ((1ull << ln) - 1ull));
            if (pos < MCAP){ mKey[pos] = ky; mIdx[pos] = ix; }
        }
    }
    __syncthreads();
    const int kM = min(mCnt, MCAP);   // == 300 by construction

    // P6: boxes for members (pred rows are L3-resident after kA) + targets
    for (int m = tid; m < kM; m += 1024){
        const float* row = p_s + (size_t)mIdx[m] * NF;
        float bx = sig_f(row[0]), by = sig_f(row[1]);
        float bw = sig_f(row[2]), bh = sig_f(row[3]);
        float hw = bw * 0.5f, hh = bh * 0.5f;
        float x1 = bx - hw, y1 = by - hh, x2 = bx + hw, y2 = by + hh;
        mB[0][m] = x1; mB[1][m] = y1; mB[2][m] = x2; mB[3][m] = y2;
        mB[4][m] = (x2 - x1) * (y2 - y1);
    }
    if (tid >= 512 && tid < 512 + NT){
        int t = tid - 512;
        const float* tb = tboxG + ((size_t)s * NT + t) * 4;
        float cx = fminf(fmaxf(tb[0], 0.f), 1.f);
        float cy = fminf(fmaxf(tb[1], 0.f), 1.f);
        float w  = fminf(fmaxf(tb[2], 0.f), 1.f);
        float h  = fminf(fmaxf(tb[3], 0.f), 1.f);
        tWH[t][0] = cx; tWH[t][1] = cy; tWH[t][2] = w; tWH[t][3] = h;
        float hw = w * 0.5f, hh = h * 0.5f;
        float x1 = cx - hw, y1 = cy - hh, x2 = cx + hw, y2 = cy + hh;
        tXY[t][0] = x1; tXY[t][1] = y1; tXY[t][2] = x2; tXY[t][3] = y2;
        tXY[t][4] = (x2 - x1) * (y2 - y1);
        int c = tclsG[(size_t)s * NT + t];
        tCl[t] = min(max(c, 0), NC - 1);
    }
    __syncthreads();

    // P7: per-target argmax over the SET by (iou desc, key desc, idx asc)
    for (int t = wv; t < NT; t += 16){
        float tx1 = tXY[t][0], ty1 = tXY[t][1], tx2 = tXY[t][2], ty2 = tXY[t][3];
        float ta  = tXY[t][4];
        float    bIou = -1.0f; unsigned bKy = 0; int bIx = 0x7FFFFFFF;
        for (int m = ln; m < kM; m += 64){
            float iw = fminf(mB[2][m], tx2) - fmaxf(mB[0][m], tx1);
            iw = fmaxf(iw, 0.0f);
            float ih = fminf(mB[3][m], ty2) - fmaxf(mB[1][m], ty1);
            ih = fmaxf(ih, 0.0f);
            float inter = iw * ih;
            float uni = mB[4][m] + ta - inter;
            float iou = (uni > 0.0f) ? (inter / uni) : 0.0f;
            unsigned ky = mKey[m]; int ix = mIdx[m];
            if (iou > bIou || (iou == bIou && (ky > bKy || (ky == bKy && ix < bIx)))){
                bIou = iou; bKy = ky; bIx = ix;
            }
        }
        #pragma unroll
        for (int off = 32; off > 0; off >>= 1){
            float    oI = __shfl_down(bIou, off);
            unsigned oK = __shfl_down(bKy,  off);
            int      oX = __shfl_down(bIx,  off);
            bool take = (ln + off < 64) &&
                        (oI > bIou || (oI == bIou && (oK > bKy || (oK == bKy && oX < bIx))));
            if (take){ bIou = oI; bKy = oK; bIx = oX; }
        }
        if (ln == 0) chosenA[t] = bIx;
    }
    __syncthreads();

    // P8: per-target contributions; duplicates: last j wins rows, cls classes union
    if (tid < NT){
        int a = chosenA[tid];
        bool last = true;
        for (int j2 = tid + 1; j2 < NT; ++j2) if (chosenA[j2] == a) last = false;
        float corr = 0.f, clsv = 0.f, boxv = 0.f;
        if (last){
            const float* row = p_s + (size_t)a * NF;
            float o = row[4];
            float spo = sp_f(o);
            corr = 2.0f * (spo - o) - 0.5f * spo;   // replace 0.5*sp with 2*(sp-x)
            unsigned mask = 0;
            for (int j2 = 0; j2 < NT; ++j2)
                if (chosenA[j2] == a) mask |= (1u << tCl[j2]);
            const float smooth_neg = (float)(0.05 / 3.0);
            for (int c = 0; c < NC; ++c){
                float x = row[5 + c];
                float t = ((mask >> c) & 1u) ? 0.95f : smooth_neg;
                clsv += sp_f(x) - x * t;
            }
            for (int c = 0; c < 4; ++c){
                float p = sig_f(row[c]);
                float d = fabsf(p - tWH[tid][c]);
                boxv += (d < 0.1f) ? (0.5f * d * d / 0.1f) : (d - 0.05f);
            }
        }
        lastJ[tid] = last ? 1 : 0;
        corrJ[tid] = corr; clsJ[tid] = clsv; boxJ[tid] = boxv;
    }
    __syncthreads();

    if (tid == 0){
        double corrS = 0, clsS = 0, boxS = 0; int np = 0;
        for (int j = 0; j < NT; ++j){
            if (lastJ[j]){ np++; corrS += corrJ[j]; clsS += clsJ[j]; boxS += boxJ[j]; }
        }
        float obj_l = (float)((0.5 * s_spsum + corrS) / (double)AP);
        float cls_l = (np > 0) ? (float)(clsS / ((double)np * NC)) : 0.f;
        float box_l = (np > 0) ? (float)(boxS / ((double)np * 4) * 2.0) : 0.f;
        lossPart[s*4 + 0] = box_l;
        lossPart[s*4 + 1] = cls_l;
        lossPart[s*4 + 2] = obj_l;
    }
}

// k5: deterministic final reduce (fixed order; stream-ordered after kB)
__global__ void k5_reduce(const float* __restrict__ lossPart, float* __restrict__ out){
    if (threadIdx.x == 0){
        double b = 0, c = 0, o = 0;
        for (int s2 = 0; s2 < NBATCH; ++s2){
            b += (double)lossPart[s2*4 + 0];
            c += (double)lossPart[s2*4 + 1];
            o += (double)lossPart[s2*4 + 2];
        }
        out[1] = (float)b; out[2] = (float)c; out[3] = (float)o;
        out[0] = (float)(b + c + o);
    }
}

// ============================ FALLBACK (round-1) ============================

__device__ __forceinline__ unsigned load_key(const unsigned* k_s, const float* p_s, int i){
    return k_s ? k_s[i] : fkey(p_s[i*NF + 4]);
}

__global__ void build_keys_kernel(const float* __restrict__ pred, unsigned* __restrict__ keys){
    int s = blockIdx.y;
    int a = blockIdx.x * 256 + threadIdx.x;
    if (a < AP){
        float o = pred[(size_t)s * (AP*NF) + (size_t)a * NF + 4];
        keys[s * AP + a] = fkey(o);
    }
}

__device__ void find_bin(unsigned* hist, unsigned* ssup, int* sbin, unsigned* sabove,
                         unsigned need, int tid){
    if (tid < 32){
        unsigned a2 = 0;
        for (int i = 0; i < 64; ++i) a2 += hist[tid*64 + i];
        ssup[tid] = a2;
    }
    __syncthreads();
    if (tid == 0){
        unsigned a2 = 0; int g = 31;
        for (; g > 0; --g){ if (a2 + ssup[g] >= need) break; a2 += ssup[g]; }
        int b = g*64 + 63;
        for (;;){ unsigned h = hist[b]; if (a2 + h >= need || b == g*64) break; a2 += h; --b; }
        *sbin = b; *sabove = a2;
    }
    __syncthreads();
}

__global__ __launch_bounds__(1024) void loss_kernel_full(
    const float* __restrict__ pred,
    const unsigned* __restrict__ keysG,
    const float* __restrict__ tboxG,
    const int*   __restrict__ tclsG,
    float* __restrict__ out)
{
    const int s   = blockIdx.x;
    const int tid = threadIdx.x;
    const float*    p_s = pred + (size_t)s * (AP*NF);
    const unsigned* k_s = keysG ? (keysG + s * AP) : nullptr;

    __shared__ unsigned hist[2048];
    __shared__ unsigned ssup[32];
    __shared__ int sbin; __shared__ unsigned sabove;
    __shared__ double wsum[16];
    __shared__ double s_spsum;
    __shared__ unsigned tkKey[KTOP]; __shared__ int tkIdx[KTOP];
    __shared__ int eqIdx[2048];
    __shared__ int nGt, nEq;
    __shared__ int sIdx[KTOP];
    __shared__ float cand[KTOP][5];
    __shared__ float tXY[NT][5];
    __shared__ float tWH[NT][4];
    __shared__ int   tCl[NT];
    __shared__ int   chosenA[NT];
    __shared__ float corrJ[NT], clsJ[NT], boxJ[NT];
    __shared__ int   lastJ[NT];

    for (int i = tid; i < 2048; i += 1024) hist[i] = 0;
    if (tid == 0){ nGt = 0; nEq = 0; }
    __syncthreads();
    double acc = 0.0;
    for (int i = tid; i < AP; i += 1024){
        unsigned ky = load_key(k_s, p_s, i);
        atomicAdd(&hist[ky >> 21], 1u);
        acc += (double)sp_f(kinv(ky));
    }
    for (int off = 32; off > 0; off >>= 1) acc += __shfl_down(acc, off);
    if ((tid & 63) == 0) wsum[tid >> 6] = acc;
    __syncthreads();
    if (tid == 0){
        double t = 0.0;
        for (int w = 0; w < 16; ++w) t += wsum[w];
        s_spsum = t;
    }
    __syncthreads();

    find_bin(hist, ssup, &sbin, &sabove, KTOP, tid);
    const int b1 = sbin; const unsigned above1 = sabove;
    const unsigned need2 = KTOP - above1;
    __syncthreads();

    for (int i = tid; i < 2048; i += 1024) hist[i] = 0;
    __syncthreads();
    for (int i = tid; i < AP; i += 1024){
        unsigned ky = load_key(k_s, p_s, i);
        if ((int)(ky >> 21) == b1) atomicAdd(&hist[(ky >> 10) & 0x7FFu], 1u);
    }
    __syncthreads();
    find_bin(hist, ssup, &sbin, &sabove, need2, tid);
    const int b2 = sbin; const unsigned above2 = sabove;
    const unsigned need3 = need2 - above2;
    const unsigned pref  = ((unsigned)b1 << 11) | (unsigned)b2;
    __syncthreads();

    for (int i = tid; i < 2048; i += 1024) hist[i] = 0;
    __syncthreads();
    for (int i = tid; i < AP; i += 1024){
        unsigned ky = load_key(k_s, p_s, i);
        if ((ky >> 10) == pref) atomicAdd(&hist[ky & 0x3FFu], 1u);
    }
    __syncthreads();
    find_bin(hist, ssup, &sbin, &sabove, need3, tid);
    const int b3 = sbin; const unsigned above3 = sabove;
    const unsigned needEq = need3 - above3;
    const unsigned T      = ((unsigned)b1 << 21) | ((unsigned)b2 << 10) | (unsigned)b3;
    const unsigned cntGt  = above1 + above2 + above3;
    __syncthreads();

    for (int i = tid; i < AP; i += 1024){
        unsigned ky = load_key(k_s, p_s, i);
        if (ky > T){
            int p = atomicAdd(&nGt, 1);
            if (p < KTOP){ tkKey[p] = ky; tkIdx[p] = i; }
        } else if (ky == T){
            int p = atomicAdd(&nEq, 1);
            if (p < 2048) eqIdx[p] = i;
        }
    }
    __syncthreads();
    {
        int ne = min(nEq, 2048);
        for (int t = tid; t < ne; t += 1024){
            int mine = eqIdx[t]; int r = 0;
            for (int j = 0; j < ne; ++j) r += (eqIdx[j] < mine) ? 1 : 0;
            if ((unsigned)r < needEq){
                int p = (int)cntGt + r;
                if (p < KTOP){ tkKey[p] = T; tkIdx[p] = mine; }
            }
        }
    }
    __syncthreads();

    if (tid < KTOP){
        unsigned myk = tkKey[tid]; int myi = tkIdx[tid];
        int r = 0;
        for (int j = 0; j < KTOP; ++j){
            unsigned kj = tkKey[j]; int ij = tkIdx[j];
            r += (kj > myk || (kj == myk && ij < myi)) ? 1 : 0;
        }
        sIdx[r] = myi;
    }
    __syncthreads();

    if (tid < KTOP){
        int a = sIdx[tid];
        const float* row = p_s + a * NF;
        float bx = sig_f(row[0]), by = sig_f(row[1]);
        float bw = sig_f(row[2]), bh = sig_f(row[3]);
        float hw = bw * 0.5f, hh = bh * 0.5f;
        float x1 = bx - hw, y1 = by - hh, x2 = bx + hw, y2 = by + hh;
        cand[tid][0] = x1; cand[tid][1] = y1; cand[tid][2] = x2; cand[tid][3] = y2;
        cand[tid][4] = (x2 - x1) * (y2 - y1);
    }
    if (tid < NT){
        const float* tb = tboxG + ((size_t)s * NT + tid) * 4;
        float cx = fminf(fmaxf(tb[0], 0.f), 1.f);
        float cy = fminf(fmaxf(tb[1], 0.f), 1.f);
        float w  = fminf(fmaxf(tb[2], 0.f), 1.f);
        float h  = fminf(fmaxf(tb[3], 0.f), 1.f);
        tWH[tid][0] = cx; tWH[tid][1] = cy; tWH[tid][2] = w; tWH[tid][3] = h;
        float hw = w * 0.5f, hh = h * 0.5f;
        float x1 = cx - hw, y1 = cy - hh, x2 = cx + hw, y2 = cy + hh;
        tXY[tid][0] = x1; tXY[tid][1] = y1; tXY[tid][2] = x2; tXY[tid][3] = y2;
        tXY[tid][4] = (x2 - x1) * (y2 - y1);
        int c = tclsG[(size_t)s * NT + tid];
        tCl[tid] = min(max(c, 0), NC - 1);
    }
    __syncthreads();

    if (tid < NT){
        float tx1 = tXY[tid][0], ty1 = tXY[tid][1], tx2 = tXY[tid][2], ty2 = tXY[tid][3];
        float ta  = tXY[tid][4];
        float best = -1.0f; int bi = 0;
        for (int i = 0; i < KTOP; ++i){
            float iw = fminf(cand[i][2], tx2) - fmaxf(cand[i][0], tx1);
            iw = fmaxf(iw, 0.0f);
            float ih = fminf(cand[i][3], ty2) - fmaxf(cand[i][1], ty1);
            ih = fmaxf(ih, 0.0f);
            float inter = iw * ih;
            float uni = cand[i][4] + ta - inter;
            float iou = (uni > 0.0f) ? (inter / uni) : 0.0f;
            if (iou > best){ best = iou; bi = i; }
        }
        chosenA[tid] = sIdx[bi];
    }
    __syncthreads();

    if (tid < NT){
        int a = chosenA[tid];
        bool last = true;
        for (int j2 = tid + 1; j2 < NT; ++j2) if (chosenA[j2] == a) last = false;
        float corr = 0.f, clsv = 0.f, boxv = 0.f;
        if (last){
            const float* row = p_s + a * NF;
            float o = row[4];
            float spo = sp_f(o);
            corr = 2.0f * (spo - o) - 0.5f * spo;
            unsigned mask = 0;
            for (int j2 = 0; j2 < NT; ++j2)
                if (chosenA[j2] == a) mask |= (1u << tCl[j2]);
            const float smooth_neg = (float)(0.05 / 3.0);
            for (int c = 0; c < NC; ++c){
                float x = row[5 + c];
                float t = ((mask >> c) & 1u) ? 0.95f : smooth_neg;
                clsv += sp_f(x) - x * t;
            }
            for (int c = 0; c < 4; ++c){
                float p = sig_f(row[c]);
                float d = fabsf(p - tWH[tid][c]);
                boxv += (d < 0.1f) ? (0.5f * d * d / 0.1f) : (d - 0.05f);
            }
        }
        lastJ[tid] = last ? 1 : 0;
        corrJ[tid] = corr; clsJ[tid] = clsv; boxJ[tid] = boxv;
    }
    __syncthreads();

    if (tid == 0){
        double corrS = 0, clsS = 0, boxS = 0; int np = 0;
        for (int j = 0; j < NT; ++j){
            if (lastJ[j]){ np++; corrS += corrJ[j]; clsS += clsJ[j]; boxS += boxJ[j]; }
        }
        float obj_l = (float)((0.5 * s_spsum + corrS) / (double)AP);
        float cls_l = (np > 0) ? (float)(clsS / ((double)np * NC)) : 0.f;
        float box_l = (np > 0) ? (float)(boxS / ((double)np * 4) * 2.0) : 0.f;
        atomicAdd(&out[1], box_l);
        atomicAdd(&out[2], cls_l);
        atomicAdd(&out[3], obj_l);
        atomicAdd(&out[0], box_l + cls_l + obj_l);
    }
}

// ============================ LAUNCH ========================================

static inline size_t align256(size_t x){ return (x + 255) & ~(size_t)255; }

extern "C" void kernel_launch(void* const* d_in, const int* in_sizes, int n_in,
                              void* d_out, int out_size, void* d_ws, size_t ws_size,
                              hipStream_t stream) {
    const float* pred = (const float*)d_in[0];
    const float* tbox = (const float*)d_in[1];
    const int*   tcls = (const int*)d_in[2];
    float* out = (float*)d_out;

    // ws layout — every byte used is fully rewritten each call (no zeroing)
    const size_t oCnt   = 0;
    const size_t oPart  = align256(oCnt + (size_t)NBATCH * NBLK1 * sizeof(int));
    const size_t oCKey  = align256(oPart + (size_t)NBATCH * NBLK1 * sizeof(double));
    const size_t oCIdx  = align256(oCKey + (size_t)NBATCH * NBLK1 * LCAP * sizeof(unsigned));
    const size_t oLoss  = align256(oCIdx + (size_t)NBATCH * NBLK1 * LCAP * sizeof(int));
    const size_t need   = oLoss + (size_t)NBATCH * 4 * sizeof(float);
    const size_t keysB  = (size_t)NBATCH * AP * sizeof(unsigned);

    if (ws_size >= need){
        char* ws = (char*)d_ws;
        int*      candCnt = (int*)     (ws + oCnt);
        double*   parts   = (double*)  (ws + oPart);
        unsigned* candKey = (unsigned*)(ws + oCKey);
        int*      candIdx = (int*)     (ws + oCIdx);
        float*    lossP   = (float*)   (ws + oLoss);

        dim3 gwA(NBLK1, NBATCH);
        kA_scan<<<gwA, 256, 0, stream>>>(pred, parts, candKey, candIdx, candCnt);
        kB_finish<<<NBATCH, 1024, 0, stream>>>(pred, tbox, tcls, candKey, candIdx,
                                               candCnt, parts, lossP);
        k5_reduce<<<1, 64, 0, stream>>>(lossP, out);
    } else {
        hipMemsetAsync(d_out, 0, (size_t)out_size * sizeof(float), stream);
        unsigned* keys = (ws_size >= keysB) ? (unsigned*)d_ws : nullptr;
        if (keys){
            dim3 grid((AP + 255) / 256, NBATCH);
            build_keys_kernel<<<grid, 256, 0, stream>>>(pred, keys);
        }
        loss_kernel_full<<<NBATCH, 1024, 0, stream>>>(pred, keys, tbox, tcls, out);
    }
}